// Round 1
// baseline (691.396 us; speedup 1.0000x reference)
//
#include <hip/hip_runtime.h>
#include <hip/hip_bf16.h>

#define H_DIM 2048
#define E_NUM 8
#define I_DIM 4096
#define TWO_I 8192
#define T_TOK 2048

#define BM 128
#define BN 64
#define BK 64

typedef __bf16 bf16x8 __attribute__((ext_vector_type(8)));
typedef float f32x4 __attribute__((ext_vector_type(4)));

static __device__ __forceinline__ unsigned short f2bs(float x) {
    __hip_bfloat16 h = __float2bfloat16(x);
    return __builtin_bit_cast(unsigned short, h);
}

#define GLL(gsrc, ldst) __builtin_amdgcn_global_load_lds( \
    (const __attribute__((address_space(1))) void*)(gsrc), \
    (__attribute__((address_space(3))) void*)(ldst), 16, 0, 0)

// ---------------- transpose f32 [R][C] -> bf16 [C][R], batched over z ----------------
__global__ __launch_bounds__(256) void transpose_kernel(
    const float* __restrict__ in, unsigned short* __restrict__ out, int R, int C) {
    __shared__ float tile[64][65];
    size_t bo = (size_t)blockIdx.z * R * C;
    const float* src = in + bo;
    unsigned short* dst = out + bo;
    int r0 = blockIdx.y * 64, c0 = blockIdx.x * 64;
    int t = threadIdx.x;
    int lr = t >> 4, lc = (t & 15) * 4;
#pragma unroll
    for (int i = 0; i < 4; i++) {
        int r = lr + i * 16;
        float4 v = *reinterpret_cast<const float4*>(src + (size_t)(r0 + r) * C + c0 + lc);
        tile[r][lc + 0] = v.x; tile[r][lc + 1] = v.y;
        tile[r][lc + 2] = v.z; tile[r][lc + 3] = v.w;
    }
    __syncthreads();
    int rc = (t & 15) * 4;
#pragma unroll
    for (int i = 0; i < 4; i++) {
        int ct = (t >> 4) + i * 16;
        ushort4 o;
        o.x = f2bs(tile[rc + 0][ct]);
        o.y = f2bs(tile[rc + 1][ct]);
        o.z = f2bs(tile[rc + 2][ct]);
        o.w = f2bs(tile[rc + 3][ct]);
        *reinterpret_cast<ushort4*>(dst + (size_t)(c0 + ct) * R + r0 + rc) = o;
    }
}

// ---------------- router: one wave per token ----------------
__global__ __launch_bounds__(256) void router_kernel(
    const float* __restrict__ hs, const float* __restrict__ rw,
    float* __restrict__ out_scores, float* __restrict__ score, int* __restrict__ eidx) {
    int tok = blockIdx.x * 4 + (threadIdx.x >> 6);
    int lane = threadIdx.x & 63;
    const float* row = hs + (size_t)tok * H_DIM;
    float acc[E_NUM];
#pragma unroll
    for (int e = 0; e < E_NUM; e++) acc[e] = 0.f;
    for (int h = lane; h < H_DIM; h += 64) {
        float a = row[h];
        const float* wr = rw + h * E_NUM;
#pragma unroll
        for (int e = 0; e < E_NUM; e++) acc[e] += a * wr[e];
    }
#pragma unroll
    for (int e = 0; e < E_NUM; e++) {
#pragma unroll
        for (int o = 32; o > 0; o >>= 1) acc[e] += __shfl_xor(acc[e], o, 64);
    }
    int best = 0; float bv = acc[0];
#pragma unroll
    for (int e = 1; e < E_NUM; e++) { if (acc[e] > bv) { bv = acc[e]; best = e; } }
    float sc = 1.f / (1.f + expf(-bv));
    if (lane < E_NUM) out_scores[(size_t)lane * T_TOK + tok] = (lane == best) ? sc : 0.f;
    if (lane == 0) { score[tok] = sc; eidx[tok] = best; }
}

// ---------------- convert hs -> bf16 (xb) and bf16(hs*score) (xs) ----------------
__global__ __launch_bounds__(256) void convert_kernel(
    const float* __restrict__ hs, const float* __restrict__ score,
    unsigned short* __restrict__ xb, unsigned short* __restrict__ xs) {
    size_t idx = (size_t)(blockIdx.x * 256 + threadIdx.x) * 8;
    float s = score[idx >> 11];
    float4 v0 = *reinterpret_cast<const float4*>(hs + idx);
    float4 v1 = *reinterpret_cast<const float4*>(hs + idx + 4);
    ushort4 b0, b1, s0, s1;
    b0.x = f2bs(v0.x); b0.y = f2bs(v0.y); b0.z = f2bs(v0.z); b0.w = f2bs(v0.w);
    b1.x = f2bs(v1.x); b1.y = f2bs(v1.y); b1.z = f2bs(v1.z); b1.w = f2bs(v1.w);
    s0.x = f2bs(v0.x * s); s0.y = f2bs(v0.y * s); s0.z = f2bs(v0.z * s); s0.w = f2bs(v0.w * s);
    s1.x = f2bs(v1.x * s); s1.y = f2bs(v1.y * s); s1.z = f2bs(v1.z * s); s1.w = f2bs(v1.w * s);
    *reinterpret_cast<ushort4*>(xb + idx) = b0;
    *reinterpret_cast<ushort4*>(xb + idx + 4) = b1;
    *reinterpret_cast<ushort4*>(xs + idx) = s0;
    *reinterpret_cast<ushort4*>(xs + idx + 4) = s1;
}

// ---------------- grouping: histogram + offsets + scatter (1 block) ----------------
__global__ void group_kernel(const int* __restrict__ eidx, int* __restrict__ perm,
                             int* __restrict__ off) {
    __shared__ int cnt[E_NUM];
    __shared__ int base[E_NUM];
    int t = threadIdx.x;
    if (t < E_NUM) cnt[t] = 0;
    __syncthreads();
    for (int i = t; i < T_TOK; i += 256) atomicAdd(&cnt[eidx[i]], 1);
    __syncthreads();
    if (t == 0) {
        int s = 0;
        for (int e = 0; e < E_NUM; e++) { base[e] = s; off[e] = s; s += cnt[e]; }
        off[E_NUM] = s;
    }
    __syncthreads();
    for (int i = t; i < T_TOK; i += 256) {
        int e = eidx[i];
        int p = atomicAdd(&base[e], 1);
        perm[p] = i;
    }
}

// ---------------- GEMM1: grouped gate_up + SwiGLU -> hmid (bf16) ----------------
// grid.x = I/BN (n-tiles over I), grid.y = slot: g = slot>>4 (0..8), mt = slot&15
__global__ __launch_bounds__(256, 2) void gemm1_kernel(
    const unsigned short* __restrict__ xb, const unsigned short* __restrict__ xs,
    const unsigned short* __restrict__ Btgu, const unsigned short* __restrict__ Sgt,
    const unsigned short* __restrict__ Sut, const int* __restrict__ perm,
    const int* __restrict__ off, unsigned short* __restrict__ hmid) {
    int nt = blockIdx.x;
    int g = blockIdx.y >> 4;
    int mt = blockIdx.y & 15;
    int rowbase, ng;
    if (g < E_NUM) { rowbase = off[g]; ng = off[g + 1] - rowbase; }
    else { rowbase = 0; ng = T_TOK; }
    int mstart = mt * BM;
    if (mstart >= ng) return;

    __shared__ unsigned short As[BM][BK];
    __shared__ unsigned short Bg[BN][BK];
    __shared__ unsigned short Bu[BN][BK];

    int tid = threadIdx.x;
    int wave = tid >> 6, lane = tid & 63;
    int wr = wave >> 1, wc = wave & 1;

    const unsigned short* Abase = (g == E_NUM) ? xb : xs;
    const unsigned short* arow[4];
#pragma unroll
    for (int j = 0; j < 4; j++) {
        int r = wave * 32 + j * 8 + (lane >> 3);
        int sr = mstart + r; sr = (sr < ng) ? sr : (ng - 1);
        int tokr = (g < E_NUM) ? perm[rowbase + sr] : sr;
        arow[j] = Abase + (size_t)tokr * H_DIM + (lane & 7) * 8;
    }
    int n0 = nt * BN;
    const unsigned short *bgrow[2], *burow[2];
#pragma unroll
    for (int j = 0; j < 2; j++) {
        int n = n0 + wave * 16 + j * 8 + (lane >> 3);
        const unsigned short* gs;
        const unsigned short* us;
        if (g < E_NUM) {
            gs = Btgu + ((size_t)g * TWO_I + n) * H_DIM;
            us = Btgu + ((size_t)g * TWO_I + I_DIM + n) * H_DIM;
        } else {
            gs = Sgt + (size_t)n * H_DIM;
            us = Sut + (size_t)n * H_DIM;
        }
        bgrow[j] = gs + (lane & 7) * 8;
        burow[j] = us + (lane & 7) * 8;
    }

    f32x4 zero = {0.f, 0.f, 0.f, 0.f};
    f32x4 accg[4][2], accu[4][2];
#pragma unroll
    for (int i = 0; i < 4; i++)
#pragma unroll
        for (int j = 0; j < 2; j++) { accg[i][j] = zero; accu[i][j] = zero; }

    for (int k0 = 0; k0 < H_DIM; k0 += BK) {
#pragma unroll
        for (int j = 0; j < 4; j++) GLL(arow[j] + k0, &As[wave * 32 + j * 8][0]);
#pragma unroll
        for (int j = 0; j < 2; j++) {
            GLL(bgrow[j] + k0, &Bg[wave * 16 + j * 8][0]);
            GLL(burow[j] + k0, &Bu[wave * 16 + j * 8][0]);
        }
        __syncthreads();
#pragma unroll
        for (int s = 0; s < 2; s++) {
            bf16x8 a[4];
#pragma unroll
            for (int i = 0; i < 4; i++)
                a[i] = *reinterpret_cast<const bf16x8*>(
                    &As[wr * 64 + i * 16 + (lane & 15)][s * 32 + (lane >> 4) * 8]);
#pragma unroll
            for (int j = 0; j < 2; j++) {
                bf16x8 bg = *reinterpret_cast<const bf16x8*>(
                    &Bg[wc * 32 + j * 16 + (lane & 15)][s * 32 + (lane >> 4) * 8]);
                bf16x8 bu = *reinterpret_cast<const bf16x8*>(
                    &Bu[wc * 32 + j * 16 + (lane & 15)][s * 32 + (lane >> 4) * 8]);
#pragma unroll
                for (int i = 0; i < 4; i++) {
                    accg[i][j] = __builtin_amdgcn_mfma_f32_16x16x32_bf16(a[i], bg, accg[i][j], 0, 0, 0);
                    accu[i][j] = __builtin_amdgcn_mfma_f32_16x16x32_bf16(a[i], bu, accu[i][j], 0, 0, 0);
                }
            }
        }
        __syncthreads();
    }
    int hbase = (g < E_NUM) ? rowbase : T_TOK;
#pragma unroll
    for (int i = 0; i < 4; i++) {
#pragma unroll
        for (int j = 0; j < 2; j++) {
#pragma unroll
            for (int r = 0; r < 4; r++) {
                int row = wr * 64 + i * 16 + (lane >> 4) * 4 + r;
                int sr = mstart + row;
                if (sr < ng) {
                    float gv = accg[i][j][r], uv = accu[i][j][r];
                    float hv = gv / (1.f + expf(-gv)) * uv;  // silu(g)*u
                    int col = n0 + wc * 32 + j * 16 + (lane & 15);
                    hmid[(size_t)(hbase + sr) * I_DIM + col] = f2bs(hv);
                }
            }
        }
    }
}

// ---------------- GEMM2: down proj. ADD=0: shared (writes), ADD=1: routed (accumulates)
template <int ADD>
__global__ __launch_bounds__(256, 2) void gemm2_kernel(
    const unsigned short* __restrict__ hmid, const unsigned short* __restrict__ Bsrc,
    const int* __restrict__ perm, const int* __restrict__ off, float* __restrict__ out) {
    int nt = blockIdx.x;
    int g, mt, rowbase, ng, hbase;
    if (ADD) {
        g = blockIdx.y >> 4; mt = blockIdx.y & 15;
        rowbase = off[g]; ng = off[g + 1] - rowbase; hbase = rowbase;
    } else {
        g = E_NUM; mt = blockIdx.y; rowbase = 0; ng = T_TOK; hbase = T_TOK;
    }
    int mstart = mt * BM;
    if (mstart >= ng) return;

    __shared__ unsigned short As[BM][BK];
    __shared__ unsigned short Bs[BN][BK];

    int tid = threadIdx.x;
    int wave = tid >> 6, lane = tid & 63;
    int wr = wave >> 1, wc = wave & 1;

    const unsigned short* arow[4];
#pragma unroll
    for (int j = 0; j < 4; j++) {
        int r = wave * 32 + j * 8 + (lane >> 3);
        int sr = mstart + r; sr = (sr < ng) ? sr : (ng - 1);
        arow[j] = hmid + (size_t)(hbase + sr) * I_DIM + (lane & 7) * 8;
    }
    int n0 = nt * BN;
    const unsigned short* brow[2];
#pragma unroll
    for (int j = 0; j < 2; j++) {
        int n = n0 + wave * 16 + j * 8 + (lane >> 3);
        const unsigned short* bs =
            ADD ? (Bsrc + ((size_t)g * H_DIM + n) * I_DIM) : (Bsrc + (size_t)n * I_DIM);
        brow[j] = bs + (lane & 7) * 8;
    }

    f32x4 zero = {0.f, 0.f, 0.f, 0.f};
    f32x4 acc[4][2];
#pragma unroll
    for (int i = 0; i < 4; i++)
#pragma unroll
        for (int j = 0; j < 2; j++) acc[i][j] = zero;

    for (int k0 = 0; k0 < I_DIM; k0 += BK) {
#pragma unroll
        for (int j = 0; j < 4; j++) GLL(arow[j] + k0, &As[wave * 32 + j * 8][0]);
#pragma unroll
        for (int j = 0; j < 2; j++) GLL(brow[j] + k0, &Bs[wave * 16 + j * 8][0]);
        __syncthreads();
#pragma unroll
        for (int s = 0; s < 2; s++) {
            bf16x8 a[4];
#pragma unroll
            for (int i = 0; i < 4; i++)
                a[i] = *reinterpret_cast<const bf16x8*>(
                    &As[wr * 64 + i * 16 + (lane & 15)][s * 32 + (lane >> 4) * 8]);
#pragma unroll
            for (int j = 0; j < 2; j++) {
                bf16x8 b = *reinterpret_cast<const bf16x8*>(
                    &Bs[wc * 32 + j * 16 + (lane & 15)][s * 32 + (lane >> 4) * 8]);
#pragma unroll
                for (int i = 0; i < 4; i++)
                    acc[i][j] = __builtin_amdgcn_mfma_f32_16x16x32_bf16(a[i], b, acc[i][j], 0, 0, 0);
            }
        }
        __syncthreads();
    }
#pragma unroll
    for (int i = 0; i < 4; i++) {
#pragma unroll
        for (int j = 0; j < 2; j++) {
#pragma unroll
            for (int r = 0; r < 4; r++) {
                int row = wr * 64 + i * 16 + (lane >> 4) * 4 + r;
                int sr = mstart + row;
                if (sr < ng) {
                    int tok = ADD ? perm[rowbase + sr] : sr;
                    int col = n0 + wc * 32 + j * 16 + (lane & 15);
                    float v = acc[i][j][r];
                    float* o = out + (size_t)tok * H_DIM + col;
                    if (ADD) *o += v; else *o = v;
                }
            }
        }
    }
}

extern "C" void kernel_launch(void* const* d_in, const int* in_sizes, int n_in,
                              void* d_out, int out_size, void* d_ws, size_t ws_size,
                              hipStream_t stream) {
    (void)in_sizes; (void)n_in; (void)out_size;
    const float* hs  = (const float*)d_in[0];
    const float* rw  = (const float*)d_in[1];
    const float* gup = (const float*)d_in[2];
    const float* dwn = (const float*)d_in[3];
    const float* sg  = (const float*)d_in[4];
    const float* su  = (const float*)d_in[5];
    const float* sd  = (const float*)d_in[6];
    float* out = (float*)d_out;
    float* out_scores = out + (size_t)T_TOK * H_DIM;

    char* w = (char*)d_ws;
    size_t o = 0;
    auto alloc = [&](size_t bytes) {
        void* p = w + o;
        o += (bytes + 255) & ~(size_t)255;
        return p;
    };
    unsigned short* Btgu = (unsigned short*)alloc((size_t)E_NUM * TWO_I * H_DIM * 2);
    unsigned short* Dt   = (unsigned short*)alloc((size_t)E_NUM * H_DIM * I_DIM * 2);
    unsigned short* Sgt  = (unsigned short*)alloc((size_t)I_DIM * H_DIM * 2);
    unsigned short* Sut  = (unsigned short*)alloc((size_t)I_DIM * H_DIM * 2);
    unsigned short* Sdt  = (unsigned short*)alloc((size_t)H_DIM * I_DIM * 2);
    unsigned short* xb   = (unsigned short*)alloc((size_t)T_TOK * H_DIM * 2);
    unsigned short* xs   = (unsigned short*)alloc((size_t)T_TOK * H_DIM * 2);
    unsigned short* hmid = (unsigned short*)alloc((size_t)2 * T_TOK * I_DIM * 2);
    float* score = (float*)alloc(T_TOK * 4);
    int* eidx    = (int*)alloc(T_TOK * 4);
    int* perm    = (int*)alloc(T_TOK * 4);
    int* off     = (int*)alloc(64 * 4);
    if (ws_size < o) return;  // insufficient workspace

    // weight transposes (f32 -> bf16, B^T layout for k-contiguous MFMA fragments)
    transpose_kernel<<<dim3(TWO_I / 64, H_DIM / 64, E_NUM), 256, 0, stream>>>(gup, Btgu, H_DIM, TWO_I);
    transpose_kernel<<<dim3(H_DIM / 64, I_DIM / 64, E_NUM), 256, 0, stream>>>(dwn, Dt, I_DIM, H_DIM);
    transpose_kernel<<<dim3(I_DIM / 64, H_DIM / 64, 1), 256, 0, stream>>>(sg, Sgt, H_DIM, I_DIM);
    transpose_kernel<<<dim3(I_DIM / 64, H_DIM / 64, 1), 256, 0, stream>>>(su, Sut, H_DIM, I_DIM);
    transpose_kernel<<<dim3(H_DIM / 64, I_DIM / 64, 1), 256, 0, stream>>>(sd, Sdt, I_DIM, H_DIM);

    router_kernel<<<T_TOK / 4, 256, 0, stream>>>(hs, rw, out_scores, score, eidx);
    convert_kernel<<<(T_TOK * H_DIM / 8) / 256, 256, 0, stream>>>(hs, score, xb, xs);
    group_kernel<<<1, 256, 0, stream>>>(eidx, perm, off);

    gemm1_kernel<<<dim3(I_DIM / BN, 9 * 16), 256, 0, stream>>>(xb, xs, Btgu, Sgt, Sut, perm, off, hmid);
    gemm2_kernel<0><<<dim3(H_DIM / BN, 16), 256, 0, stream>>>(hmid, Sdt, perm, off, out);
    gemm2_kernel<1><<<dim3(H_DIM / BN, E_NUM * 16), 256, 0, stream>>>(hmid, Dt, perm, off, out);
}

// Round 2
// 604.244 us; speedup vs baseline: 1.1442x; 1.1442x over previous
//
#include <hip/hip_runtime.h>
#include <hip/hip_bf16.h>

#define H_DIM 2048
#define E_NUM 8
#define I_DIM 4096
#define TWO_I 8192
#define T_TOK 2048

#define BM 256
#define BN 64
#define BK 64

typedef __bf16 bf16x8 __attribute__((ext_vector_type(8)));
typedef float f32x4 __attribute__((ext_vector_type(4)));

static __device__ __forceinline__ unsigned short f2bs(float x) {
    __hip_bfloat16 h = __float2bfloat16(x);
    return __builtin_bit_cast(unsigned short, h);
}

#define GLL(gsrc, ldst) __builtin_amdgcn_global_load_lds( \
    (const __attribute__((address_space(1))) void*)(gsrc), \
    (__attribute__((address_space(3))) void*)(ldst), 16, 0, 0)

// XOR swizzle for transposed B tiles in LDS: conflict-free reads, ~2-way writes
#define BSWZ(n) (((((n) & 7) ^ (((n) >> 2) & 7))) << 4)

// Stage a BK x BN f32 tile (native [K][N], row stride ldb) into LDS as
// bf16 [BN][BK] (k-contiguous), XOR-swizzled. src points at (k=0, n=n0).
static __device__ __forceinline__ void stage_b(
    const float* __restrict__ src, size_t ldb, unsigned short* __restrict__ Bs,
    int wave, int lane) {
    int k0 = wave * 16 + ((lane >> 4) << 2);   // 4 k-rows per lane
    int nb = (lane & 15) << 2;                 // 4 n-cols per lane
    const float* p = src + (size_t)k0 * ldb + nb;
    float4 r0 = *reinterpret_cast<const float4*>(p);
    float4 r1 = *reinterpret_cast<const float4*>(p + ldb);
    float4 r2 = *reinterpret_cast<const float4*>(p + 2 * (size_t)ldb);
    float4 r3 = *reinterpret_cast<const float4*>(p + 3 * (size_t)ldb);
    ushort4 o;
    int n, off;
    n = nb + 0;
    o.x = f2bs(r0.x); o.y = f2bs(r1.x); o.z = f2bs(r2.x); o.w = f2bs(r3.x);
    off = (n * 128 + k0 * 2) ^ BSWZ(n);
    *reinterpret_cast<ushort4*>((char*)Bs + off) = o;
    n = nb + 1;
    o.x = f2bs(r0.y); o.y = f2bs(r1.y); o.z = f2bs(r2.y); o.w = f2bs(r3.y);
    off = (n * 128 + k0 * 2) ^ BSWZ(n);
    *reinterpret_cast<ushort4*>((char*)Bs + off) = o;
    n = nb + 2;
    o.x = f2bs(r0.z); o.y = f2bs(r1.z); o.z = f2bs(r2.z); o.w = f2bs(r3.z);
    off = (n * 128 + k0 * 2) ^ BSWZ(n);
    *reinterpret_cast<ushort4*>((char*)Bs + off) = o;
    n = nb + 3;
    o.x = f2bs(r0.w); o.y = f2bs(r1.w); o.z = f2bs(r2.w); o.w = f2bs(r3.w);
    off = (n * 128 + k0 * 2) ^ BSWZ(n);
    *reinterpret_cast<ushort4*>((char*)Bs + off) = o;
}

static __device__ __forceinline__ bf16x8 bload(
    const unsigned short* __restrict__ Bs, int n, int s, int h) {
    int off = (n * 128 + s * 64 + h * 16) ^ BSWZ(n);
    return *reinterpret_cast<const bf16x8*>((const char*)Bs + off);
}

// ---------------- router: one wave per token ----------------
__global__ __launch_bounds__(256) void router_kernel(
    const float* __restrict__ hs, const float* __restrict__ rw,
    float* __restrict__ out_scores, float* __restrict__ score, int* __restrict__ eidx) {
    int tok = blockIdx.x * 4 + (threadIdx.x >> 6);
    int lane = threadIdx.x & 63;
    const float* row = hs + (size_t)tok * H_DIM;
    float acc[E_NUM];
#pragma unroll
    for (int e = 0; e < E_NUM; e++) acc[e] = 0.f;
    for (int h = lane; h < H_DIM; h += 64) {
        float a = row[h];
        const float* wr = rw + h * E_NUM;
#pragma unroll
        for (int e = 0; e < E_NUM; e++) acc[e] += a * wr[e];
    }
#pragma unroll
    for (int e = 0; e < E_NUM; e++) {
#pragma unroll
        for (int o = 32; o > 0; o >>= 1) acc[e] += __shfl_xor(acc[e], o, 64);
    }
    int best = 0; float bv = acc[0];
#pragma unroll
    for (int e = 1; e < E_NUM; e++) { if (acc[e] > bv) { bv = acc[e]; best = e; } }
    float sc = 1.f / (1.f + expf(-bv));
    if (lane < E_NUM) out_scores[(size_t)lane * T_TOK + tok] = (lane == best) ? sc : 0.f;
    if (lane == 0) { score[tok] = sc; eidx[tok] = best; }
}

// ---------------- convert hs -> bf16 (xb) and bf16(hs*score) (xs) ----------------
__global__ __launch_bounds__(256) void convert_kernel(
    const float* __restrict__ hs, const float* __restrict__ score,
    unsigned short* __restrict__ xb, unsigned short* __restrict__ xs) {
    size_t idx = (size_t)(blockIdx.x * 256 + threadIdx.x) * 8;
    float s = score[idx >> 11];
    float4 v0 = *reinterpret_cast<const float4*>(hs + idx);
    float4 v1 = *reinterpret_cast<const float4*>(hs + idx + 4);
    ushort4 b0, b1, s0, s1;
    b0.x = f2bs(v0.x); b0.y = f2bs(v0.y); b0.z = f2bs(v0.z); b0.w = f2bs(v0.w);
    b1.x = f2bs(v1.x); b1.y = f2bs(v1.y); b1.z = f2bs(v1.z); b1.w = f2bs(v1.w);
    s0.x = f2bs(v0.x * s); s0.y = f2bs(v0.y * s); s0.z = f2bs(v0.z * s); s0.w = f2bs(v0.w * s);
    s1.x = f2bs(v1.x * s); s1.y = f2bs(v1.y * s); s1.z = f2bs(v1.z * s); s1.w = f2bs(v1.w * s);
    *reinterpret_cast<ushort4*>(xb + idx) = b0;
    *reinterpret_cast<ushort4*>(xb + idx + 4) = b1;
    *reinterpret_cast<ushort4*>(xs + idx) = s0;
    *reinterpret_cast<ushort4*>(xs + idx + 4) = s1;
}

// ---------------- grouping: histogram + offsets + scatter (1 block) ----------------
__global__ void group_kernel(const int* __restrict__ eidx, int* __restrict__ perm,
                             int* __restrict__ off) {
    __shared__ int cnt[E_NUM];
    __shared__ int base[E_NUM];
    int t = threadIdx.x;
    if (t < E_NUM) cnt[t] = 0;
    __syncthreads();
    for (int i = t; i < T_TOK; i += 256) atomicAdd(&cnt[eidx[i]], 1);
    __syncthreads();
    if (t == 0) {
        int s = 0;
        for (int e = 0; e < E_NUM; e++) { base[e] = s; off[e] = s; s += cnt[e]; }
        off[E_NUM] = s;
    }
    __syncthreads();
    for (int i = t; i < T_TOK; i += 256) {
        int e = eidx[i];
        int p = atomicAdd(&base[e], 1);
        perm[p] = i;
    }
}

// ---------------- GEMM1: grouped gate_up (f32 weights, fused cvt) + SwiGLU -> hmid
// grid.x = I/BN, grid.y = slot: g = slot>>3 (0..8), mt = slot&7
__global__ __launch_bounds__(256, 2) void gemm1_kernel(
    const unsigned short* __restrict__ xb, const unsigned short* __restrict__ xs,
    const float* __restrict__ gup, const float* __restrict__ sg,
    const float* __restrict__ su, const int* __restrict__ perm,
    const int* __restrict__ off, unsigned short* __restrict__ hmid) {
    int nt = blockIdx.x;
    int g = blockIdx.y >> 3;
    int mt = blockIdx.y & 7;
    int rowbase, ng;
    if (g < E_NUM) { rowbase = off[g]; ng = off[g + 1] - rowbase; }
    else { rowbase = 0; ng = T_TOK; }
    int mstart = mt * BM;
    if (mstart >= ng) return;

    __shared__ unsigned short As[BM][BK];
    __shared__ unsigned short Bg[BN * BK];
    __shared__ unsigned short Bu[BN * BK];

    int tid = threadIdx.x;
    int wave = tid >> 6, lane = tid & 63;
    int h = lane >> 4, ln = lane & 15;

    const unsigned short* Abase = (g == E_NUM) ? xb : xs;
    unsigned int aoff[8];
#pragma unroll
    for (int j = 0; j < 8; j++) {
        int r = wave * 64 + j * 8 + (lane >> 3);
        int sr = mstart + r; sr = (sr < ng) ? sr : (ng - 1);
        int tokr = (g < E_NUM) ? perm[rowbase + sr] : sr;
        aoff[j] = (unsigned int)tokr * H_DIM + (lane & 7) * 8;
    }
    int n0 = nt * BN;
    const float* gbase;
    const float* ubase;
    size_t ldb;
    if (g < E_NUM) {
        gbase = gup + (size_t)g * H_DIM * TWO_I + n0;
        ubase = gbase + I_DIM;
        ldb = TWO_I;
    } else {
        gbase = sg + n0;
        ubase = su + n0;
        ldb = I_DIM;
    }

    f32x4 zero = {0.f, 0.f, 0.f, 0.f};
    f32x4 accg[4][4], accu[4][4];
#pragma unroll
    for (int i = 0; i < 4; i++)
#pragma unroll
        for (int j = 0; j < 4; j++) { accg[i][j] = zero; accu[i][j] = zero; }

    for (int k0 = 0; k0 < H_DIM; k0 += BK) {
#pragma unroll
        for (int j = 0; j < 8; j++) GLL(Abase + aoff[j] + k0, &As[wave * 64 + j * 8][0]);
        stage_b(gbase + (size_t)k0 * ldb, ldb, Bg, wave, lane);
        stage_b(ubase + (size_t)k0 * ldb, ldb, Bu, wave, lane);
        __syncthreads();
#pragma unroll
        for (int s = 0; s < 2; s++) {
            bf16x8 a[4];
#pragma unroll
            for (int i = 0; i < 4; i++)
                a[i] = *reinterpret_cast<const bf16x8*>(
                    &As[wave * 64 + i * 16 + ln][s * 32 + h * 8]);
#pragma unroll
            for (int j = 0; j < 4; j++) {
                bf16x8 bg = bload(Bg, j * 16 + ln, s, h);
#pragma unroll
                for (int i = 0; i < 4; i++)
                    accg[i][j] = __builtin_amdgcn_mfma_f32_16x16x32_bf16(a[i], bg, accg[i][j], 0, 0, 0);
            }
#pragma unroll
            for (int j = 0; j < 4; j++) {
                bf16x8 bu = bload(Bu, j * 16 + ln, s, h);
#pragma unroll
                for (int i = 0; i < 4; i++)
                    accu[i][j] = __builtin_amdgcn_mfma_f32_16x16x32_bf16(a[i], bu, accu[i][j], 0, 0, 0);
            }
        }
        __syncthreads();
    }
    int hbase = (g < E_NUM) ? rowbase : T_TOK;
#pragma unroll
    for (int i = 0; i < 4; i++) {
#pragma unroll
        for (int j = 0; j < 4; j++) {
#pragma unroll
            for (int r = 0; r < 4; r++) {
                int row = wave * 64 + i * 16 + h * 4 + r;
                int sr = mstart + row;
                if (sr < ng) {
                    float gv = accg[i][j][r], uv = accu[i][j][r];
                    float hv = gv / (1.f + expf(-gv)) * uv;  // silu(g)*u
                    int col = n0 + j * 16 + ln;
                    hmid[(size_t)(hbase + sr) * I_DIM + col] = f2bs(hv);
                }
            }
        }
    }
}

// ---------------- GEMM2: down proj (f32 weights, fused cvt).
// ADD=0: shared (writes), grid.y = mt (0..7). ADD=1: routed (accumulates), grid.y = g*8+mt
template <int ADD>
__global__ __launch_bounds__(256, 2) void gemm2_kernel(
    const unsigned short* __restrict__ hmid, const float* __restrict__ dwn,
    const float* __restrict__ sd, const int* __restrict__ perm,
    const int* __restrict__ off, float* __restrict__ out) {
    int nt = blockIdx.x;
    int g, mt, rowbase, ng, hbase;
    if (ADD) {
        g = blockIdx.y >> 3; mt = blockIdx.y & 7;
        rowbase = off[g]; ng = off[g + 1] - rowbase; hbase = rowbase;
    } else {
        g = E_NUM; mt = blockIdx.y; rowbase = 0; ng = T_TOK; hbase = T_TOK;
    }
    int mstart = mt * BM;
    if (mstart >= ng) return;

    __shared__ unsigned short As[BM][BK];
    __shared__ unsigned short Bs[BN * BK];

    int tid = threadIdx.x;
    int wave = tid >> 6, lane = tid & 63;
    int h = lane >> 4, ln = lane & 15;

    unsigned int aoff[8];
#pragma unroll
    for (int j = 0; j < 8; j++) {
        int r = wave * 64 + j * 8 + (lane >> 3);
        int sr = mstart + r; sr = (sr < ng) ? sr : (ng - 1);
        aoff[j] = (unsigned int)(hbase + sr) * I_DIM + (lane & 7) * 8;
    }
    int n0 = nt * BN;
    const float* bbase = ADD ? (dwn + (size_t)g * I_DIM * H_DIM + n0) : (sd + n0);

    f32x4 zero = {0.f, 0.f, 0.f, 0.f};
    f32x4 acc[4][4];
#pragma unroll
    for (int i = 0; i < 4; i++)
#pragma unroll
        for (int j = 0; j < 4; j++) acc[i][j] = zero;

    for (int k0 = 0; k0 < I_DIM; k0 += BK) {
#pragma unroll
        for (int j = 0; j < 8; j++) GLL(hmid + aoff[j] + k0, &As[wave * 64 + j * 8][0]);
        stage_b(bbase + (size_t)k0 * H_DIM, H_DIM, Bs, wave, lane);
        __syncthreads();
#pragma unroll
        for (int s = 0; s < 2; s++) {
            bf16x8 a[4];
#pragma unroll
            for (int i = 0; i < 4; i++)
                a[i] = *reinterpret_cast<const bf16x8*>(
                    &As[wave * 64 + i * 16 + ln][s * 32 + h * 8]);
#pragma unroll
            for (int j = 0; j < 4; j++) {
                bf16x8 b = bload(Bs, j * 16 + ln, s, h);
#pragma unroll
                for (int i = 0; i < 4; i++)
                    acc[i][j] = __builtin_amdgcn_mfma_f32_16x16x32_bf16(a[i], b, acc[i][j], 0, 0, 0);
            }
        }
        __syncthreads();
    }
#pragma unroll
    for (int i = 0; i < 4; i++) {
#pragma unroll
        for (int j = 0; j < 4; j++) {
#pragma unroll
            for (int r = 0; r < 4; r++) {
                int row = wave * 64 + i * 16 + h * 4 + r;
                int sr = mstart + row;
                if (sr < ng) {
                    int tok = ADD ? perm[rowbase + sr] : sr;
                    int col = n0 + j * 16 + ln;
                    float v = acc[i][j][r];
                    float* o = out + (size_t)tok * H_DIM + col;
                    if (ADD) *o += v; else *o = v;
                }
            }
        }
    }
}

extern "C" void kernel_launch(void* const* d_in, const int* in_sizes, int n_in,
                              void* d_out, int out_size, void* d_ws, size_t ws_size,
                              hipStream_t stream) {
    (void)in_sizes; (void)n_in; (void)out_size;
    const float* hs  = (const float*)d_in[0];
    const float* rw  = (const float*)d_in[1];
    const float* gup = (const float*)d_in[2];
    const float* dwn = (const float*)d_in[3];
    const float* sg  = (const float*)d_in[4];
    const float* su  = (const float*)d_in[5];
    const float* sd  = (const float*)d_in[6];
    float* out = (float*)d_out;
    float* out_scores = out + (size_t)T_TOK * H_DIM;

    char* w = (char*)d_ws;
    size_t o = 0;
    auto alloc = [&](size_t bytes) {
        void* p = w + o;
        o += (bytes + 255) & ~(size_t)255;
        return p;
    };
    unsigned short* xb   = (unsigned short*)alloc((size_t)T_TOK * H_DIM * 2);
    unsigned short* xs   = (unsigned short*)alloc((size_t)T_TOK * H_DIM * 2);
    unsigned short* hmid = (unsigned short*)alloc((size_t)2 * T_TOK * I_DIM * 2);
    float* score = (float*)alloc(T_TOK * 4);
    int* eidx    = (int*)alloc(T_TOK * 4);
    int* perm    = (int*)alloc(T_TOK * 4);
    int* off     = (int*)alloc(64 * 4);
    if (ws_size < o) return;  // insufficient workspace

    router_kernel<<<T_TOK / 4, 256, 0, stream>>>(hs, rw, out_scores, score, eidx);
    convert_kernel<<<(T_TOK * H_DIM / 8) / 256, 256, 0, stream>>>(hs, score, xb, xs);
    group_kernel<<<1, 256, 0, stream>>>(eidx, perm, off);

    gemm1_kernel<<<dim3(I_DIM / BN, 9 * 8), 256, 0, stream>>>(
        xb, xs, gup, sg, su, perm, off, hmid);
    gemm2_kernel<0><<<dim3(H_DIM / BN, 8), 256, 0, stream>>>(hmid, dwn, sd, perm, off, out);
    gemm2_kernel<1><<<dim3(H_DIM / BN, E_NUM * 8), 256, 0, stream>>>(hmid, dwn, sd, perm, off, out);
}

// Round 3
// 583.465 us; speedup vs baseline: 1.1850x; 1.0356x over previous
//
#include <hip/hip_runtime.h>
#include <hip/hip_bf16.h>

#define H_DIM 2048
#define E_NUM 8
#define I_DIM 4096
#define TWO_I 8192
#define T_TOK 2048

#define BM 256
#define BN 64
#define BK 64

typedef __bf16 bf16x8 __attribute__((ext_vector_type(8)));
typedef float f32x4 __attribute__((ext_vector_type(4)));

static __device__ __forceinline__ unsigned short f2bs(float x) {
    __hip_bfloat16 h = __float2bfloat16(x);
    return __builtin_bit_cast(unsigned short, h);
}

#define GLL(gsrc, ldst) __builtin_amdgcn_global_load_lds( \
    (const __attribute__((address_space(1))) void*)(gsrc), \
    (__attribute__((address_space(3))) void*)(ldst), 16, 0, 0)

// XOR swizzle for transposed B tiles in LDS: conflict-free reads, ~2-way writes
#define BSWZ(n) (((((n) & 7) ^ (((n) >> 2) & 7))) << 4)

// A-tile swizzle: row-major [row][BK], physical k-chunk = logical ^ (row&7).
// GLL source side: lane l supplies logical chunk (l&7)^((l>>3)&7) (row&7 == (l>>3)&7).
// Read side: byte offset ^= (row&7)<<4 with row&7 == (lane&15)&7.
#define A_SRC_CHUNK(lane) ((((lane) & 7) ^ (((lane) >> 3) & 7)) * 8)

// Stage a BK x BN f32 tile (native [K][N], row stride ldb) into LDS as
// bf16 [BN][BK] (k-contiguous), XOR-swizzled. src points at (k=0, n=n0).
static __device__ __forceinline__ void stage_b(
    const float* __restrict__ src, size_t ldb, unsigned short* __restrict__ Bs,
    int wave, int lane) {
    int k0 = wave * 16 + ((lane >> 4) << 2);   // 4 k-rows per lane
    int nb = (lane & 15) << 2;                 // 4 n-cols per lane
    const float* p = src + (size_t)k0 * ldb + nb;
    float4 r0 = *reinterpret_cast<const float4*>(p);
    float4 r1 = *reinterpret_cast<const float4*>(p + ldb);
    float4 r2 = *reinterpret_cast<const float4*>(p + 2 * (size_t)ldb);
    float4 r3 = *reinterpret_cast<const float4*>(p + 3 * (size_t)ldb);
    ushort4 o;
    int n, off;
    n = nb + 0;
    o.x = f2bs(r0.x); o.y = f2bs(r1.x); o.z = f2bs(r2.x); o.w = f2bs(r3.x);
    off = (n * 128 + k0 * 2) ^ BSWZ(n);
    *reinterpret_cast<ushort4*>((char*)Bs + off) = o;
    n = nb + 1;
    o.x = f2bs(r0.y); o.y = f2bs(r1.y); o.z = f2bs(r2.y); o.w = f2bs(r3.y);
    off = (n * 128 + k0 * 2) ^ BSWZ(n);
    *reinterpret_cast<ushort4*>((char*)Bs + off) = o;
    n = nb + 2;
    o.x = f2bs(r0.z); o.y = f2bs(r1.z); o.z = f2bs(r2.z); o.w = f2bs(r3.z);
    off = (n * 128 + k0 * 2) ^ BSWZ(n);
    *reinterpret_cast<ushort4*>((char*)Bs + off) = o;
    n = nb + 3;
    o.x = f2bs(r0.w); o.y = f2bs(r1.w); o.z = f2bs(r2.w); o.w = f2bs(r3.w);
    off = (n * 128 + k0 * 2) ^ BSWZ(n);
    *reinterpret_cast<ushort4*>((char*)Bs + off) = o;
}

static __device__ __forceinline__ bf16x8 bload(
    const unsigned short* __restrict__ Bs, int n, int s, int h) {
    int off = (n * 128 + s * 64 + h * 16) ^ BSWZ(n);
    return *reinterpret_cast<const bf16x8*>((const char*)Bs + off);
}

static __device__ __forceinline__ bf16x8 aload(
    const unsigned short* __restrict__ As, int row, int s, int h) {
    int off = row * 128 + ((s * 64 + h * 16) ^ ((row & 7) << 4));
    return *reinterpret_cast<const bf16x8*>((const char*)As + off);
}

// ---------------- fused router + convert: one wave per token ----------------
__global__ __launch_bounds__(256) void router_convert_kernel(
    const float* __restrict__ hs, const float* __restrict__ rw,
    float* __restrict__ out_scores, int* __restrict__ eidx,
    unsigned short* __restrict__ xb, unsigned short* __restrict__ xs) {
    int tok = blockIdx.x * 4 + (threadIdx.x >> 6);
    int lane = threadIdx.x & 63;
    const float* row = hs + (size_t)tok * H_DIM;
    float4 v[8];
    float acc[E_NUM];
#pragma unroll
    for (int e = 0; e < E_NUM; e++) acc[e] = 0.f;
#pragma unroll
    for (int i = 0; i < 8; i++) {
        int hb = i * 256 + lane * 4;
        v[i] = *reinterpret_cast<const float4*>(row + hb);
        const float* w0 = rw + (size_t)hb * E_NUM;
#pragma unroll
        for (int e = 0; e < E_NUM; e++) {
            acc[e] += v[i].x * w0[e] + v[i].y * w0[E_NUM + e] +
                      v[i].z * w0[2 * E_NUM + e] + v[i].w * w0[3 * E_NUM + e];
        }
    }
#pragma unroll
    for (int e = 0; e < E_NUM; e++) {
#pragma unroll
        for (int o = 32; o > 0; o >>= 1) acc[e] += __shfl_xor(acc[e], o, 64);
    }
    int best = 0; float bv = acc[0];
#pragma unroll
    for (int e = 1; e < E_NUM; e++) { if (acc[e] > bv) { bv = acc[e]; best = e; } }
    float sc = 1.f / (1.f + expf(-bv));
    if (lane < E_NUM) out_scores[(size_t)lane * T_TOK + tok] = (lane == best) ? sc : 0.f;
    if (lane == 0) eidx[tok] = best;
    unsigned short* xbr = xb + (size_t)tok * H_DIM;
    unsigned short* xsr = xs + (size_t)tok * H_DIM;
#pragma unroll
    for (int i = 0; i < 8; i++) {
        int hb = i * 256 + lane * 4;
        ushort4 b, s4;
        b.x = f2bs(v[i].x); b.y = f2bs(v[i].y); b.z = f2bs(v[i].z); b.w = f2bs(v[i].w);
        s4.x = f2bs(v[i].x * sc); s4.y = f2bs(v[i].y * sc);
        s4.z = f2bs(v[i].z * sc); s4.w = f2bs(v[i].w * sc);
        *reinterpret_cast<ushort4*>(xbr + hb) = b;
        *reinterpret_cast<ushort4*>(xsr + hb) = s4;
    }
}

// ---------------- grouping: histogram + offsets + scatter (1 block) ----------------
__global__ void group_kernel(const int* __restrict__ eidx, int* __restrict__ perm,
                             int* __restrict__ off) {
    __shared__ int cnt[E_NUM];
    __shared__ int base[E_NUM];
    int t = threadIdx.x;
    if (t < E_NUM) cnt[t] = 0;
    __syncthreads();
    for (int i = t; i < T_TOK; i += 256) atomicAdd(&cnt[eidx[i]], 1);
    __syncthreads();
    if (t == 0) {
        int s = 0;
        for (int e = 0; e < E_NUM; e++) { base[e] = s; off[e] = s; s += cnt[e]; }
        off[E_NUM] = s;
    }
    __syncthreads();
    for (int i = t; i < T_TOK; i += 256) {
        int e = eidx[i];
        int p = atomicAdd(&base[e], 1);
        perm[p] = i;
    }
}

// ---------------- GEMM1: grouped gate_up (f32 weights, fused cvt) + SwiGLU -> hmid
// grid.x = I/BN, grid.y = slot: g = slot>>3 (0..8), mt = slot&7
__global__ __launch_bounds__(256, 2) void gemm1_kernel(
    const unsigned short* __restrict__ xb, const unsigned short* __restrict__ xs,
    const float* __restrict__ gup, const float* __restrict__ sg,
    const float* __restrict__ su, const int* __restrict__ perm,
    const int* __restrict__ off, unsigned short* __restrict__ hmid) {
    int nt = blockIdx.x;
    int g = blockIdx.y >> 3;
    int mt = blockIdx.y & 7;
    int rowbase, ng;
    if (g < E_NUM) { rowbase = off[g]; ng = off[g + 1] - rowbase; }
    else { rowbase = 0; ng = T_TOK; }
    int mstart = mt * BM;
    if (mstart >= ng) return;

    __shared__ unsigned short As[BM][BK];
    __shared__ unsigned short Bg[BN * BK];
    __shared__ unsigned short Bu[BN * BK];

    int tid = threadIdx.x;
    int wave = tid >> 6, lane = tid & 63;
    int h = lane >> 4, ln = lane & 15;

    const unsigned short* Abase = (g == E_NUM) ? xb : xs;
    unsigned int aoff[8];
#pragma unroll
    for (int j = 0; j < 8; j++) {
        int r = wave * 64 + j * 8 + (lane >> 3);
        int sr = mstart + r; sr = (sr < ng) ? sr : (ng - 1);
        int tokr = (g < E_NUM) ? perm[rowbase + sr] : sr;
        aoff[j] = (unsigned int)tokr * H_DIM + A_SRC_CHUNK(lane);
    }
    int n0 = nt * BN;
    const float* gbase;
    const float* ubase;
    size_t ldb;
    if (g < E_NUM) {
        gbase = gup + (size_t)g * H_DIM * TWO_I + n0;
        ubase = gbase + I_DIM;
        ldb = TWO_I;
    } else {
        gbase = sg + n0;
        ubase = su + n0;
        ldb = I_DIM;
    }

    f32x4 zero = {0.f, 0.f, 0.f, 0.f};
    f32x4 accg[4][4], accu[4][4];
#pragma unroll
    for (int i = 0; i < 4; i++)
#pragma unroll
        for (int j = 0; j < 4; j++) { accg[i][j] = zero; accu[i][j] = zero; }

    for (int k0 = 0; k0 < H_DIM; k0 += BK) {
#pragma unroll
        for (int j = 0; j < 8; j++) GLL(Abase + aoff[j] + k0, &As[wave * 64 + j * 8][0]);
        stage_b(gbase + (size_t)k0 * ldb, ldb, Bg, wave, lane);
        stage_b(ubase + (size_t)k0 * ldb, ldb, Bu, wave, lane);
        __syncthreads();
#pragma unroll
        for (int s = 0; s < 2; s++) {
            bf16x8 a[4];
#pragma unroll
            for (int i = 0; i < 4; i++)
                a[i] = aload(&As[0][0], wave * 64 + i * 16 + ln, s, h);
#pragma unroll
            for (int j = 0; j < 4; j++) {
                bf16x8 bg = bload(Bg, j * 16 + ln, s, h);
#pragma unroll
                for (int i = 0; i < 4; i++)
                    accg[i][j] = __builtin_amdgcn_mfma_f32_16x16x32_bf16(a[i], bg, accg[i][j], 0, 0, 0);
            }
#pragma unroll
            for (int j = 0; j < 4; j++) {
                bf16x8 bu = bload(Bu, j * 16 + ln, s, h);
#pragma unroll
                for (int i = 0; i < 4; i++)
                    accu[i][j] = __builtin_amdgcn_mfma_f32_16x16x32_bf16(a[i], bu, accu[i][j], 0, 0, 0);
            }
        }
        __syncthreads();
    }
    int hbase = (g < E_NUM) ? rowbase : T_TOK;
#pragma unroll
    for (int i = 0; i < 4; i++) {
#pragma unroll
        for (int j = 0; j < 4; j++) {
#pragma unroll
            for (int r = 0; r < 4; r++) {
                int row = wave * 64 + i * 16 + h * 4 + r;
                int sr = mstart + row;
                if (sr < ng) {
                    float gv = accg[i][j][r], uv = accu[i][j][r];
                    float hv = gv / (1.f + expf(-gv)) * uv;  // silu(g)*u
                    int col = n0 + j * 16 + ln;
                    hmid[(size_t)(hbase + sr) * I_DIM + col] = f2bs(hv);
                }
            }
        }
    }
}

// ---------------- GEMM2: down proj (f32 weights, fused cvt).
// ADD=0: shared (writes), grid.y = mt (0..7). ADD=1: routed (accumulates), grid.y = g*8+mt
template <int ADD>
__global__ __launch_bounds__(256, 2) void gemm2_kernel(
    const unsigned short* __restrict__ hmid, const float* __restrict__ dwn,
    const float* __restrict__ sd, const int* __restrict__ perm,
    const int* __restrict__ off, float* __restrict__ out) {
    int nt = blockIdx.x;
    int g, mt, rowbase, ng, hbase;
    if (ADD) {
        g = blockIdx.y >> 3; mt = blockIdx.y & 7;
        rowbase = off[g]; ng = off[g + 1] - rowbase; hbase = rowbase;
    } else {
        g = E_NUM; mt = blockIdx.y; rowbase = 0; ng = T_TOK; hbase = T_TOK;
    }
    int mstart = mt * BM;
    if (mstart >= ng) return;

    __shared__ unsigned short As[BM][BK];
    __shared__ unsigned short Bs[BN * BK];

    int tid = threadIdx.x;
    int wave = tid >> 6, lane = tid & 63;
    int h = lane >> 4, ln = lane & 15;

    unsigned int aoff[8];
#pragma unroll
    for (int j = 0; j < 8; j++) {
        int r = wave * 64 + j * 8 + (lane >> 3);
        int sr = mstart + r; sr = (sr < ng) ? sr : (ng - 1);
        aoff[j] = (unsigned int)(hbase + sr) * I_DIM + A_SRC_CHUNK(lane);
    }
    int n0 = nt * BN;
    const float* bbase = ADD ? (dwn + (size_t)g * I_DIM * H_DIM + n0) : (sd + n0);

    f32x4 zero = {0.f, 0.f, 0.f, 0.f};
    f32x4 acc[4][4];
#pragma unroll
    for (int i = 0; i < 4; i++)
#pragma unroll
        for (int j = 0; j < 4; j++) acc[i][j] = zero;

    for (int k0 = 0; k0 < I_DIM; k0 += BK) {
#pragma unroll
        for (int j = 0; j < 8; j++) GLL(hmid + aoff[j] + k0, &As[wave * 64 + j * 8][0]);
        stage_b(bbase + (size_t)k0 * H_DIM, H_DIM, Bs, wave, lane);
        __syncthreads();
#pragma unroll
        for (int s = 0; s < 2; s++) {
            bf16x8 a[4];
#pragma unroll
            for (int i = 0; i < 4; i++)
                a[i] = aload(&As[0][0], wave * 64 + i * 16 + ln, s, h);
#pragma unroll
            for (int j = 0; j < 4; j++) {
                bf16x8 b = bload(Bs, j * 16 + ln, s, h);
#pragma unroll
                for (int i = 0; i < 4; i++)
                    acc[i][j] = __builtin_amdgcn_mfma_f32_16x16x32_bf16(a[i], b, acc[i][j], 0, 0, 0);
            }
        }
        __syncthreads();
    }
#pragma unroll
    for (int i = 0; i < 4; i++) {
#pragma unroll
        for (int j = 0; j < 4; j++) {
#pragma unroll
            for (int r = 0; r < 4; r++) {
                int row = wave * 64 + i * 16 + h * 4 + r;
                int sr = mstart + row;
                if (sr < ng) {
                    int tok = ADD ? perm[rowbase + sr] : sr;
                    int col = n0 + j * 16 + ln;
                    float v = acc[i][j][r];
                    float* o = out + (size_t)tok * H_DIM + col;
                    if (ADD) *o += v; else *o = v;
                }
            }
        }
    }
}

extern "C" void kernel_launch(void* const* d_in, const int* in_sizes, int n_in,
                              void* d_out, int out_size, void* d_ws, size_t ws_size,
                              hipStream_t stream) {
    (void)in_sizes; (void)n_in; (void)out_size;
    const float* hs  = (const float*)d_in[0];
    const float* rw  = (const float*)d_in[1];
    const float* gup = (const float*)d_in[2];
    const float* dwn = (const float*)d_in[3];
    const float* sg  = (const float*)d_in[4];
    const float* su  = (const float*)d_in[5];
    const float* sd  = (const float*)d_in[6];
    float* out = (float*)d_out;
    float* out_scores = out + (size_t)T_TOK * H_DIM;

    char* w = (char*)d_ws;
    size_t o = 0;
    auto alloc = [&](size_t bytes) {
        void* p = w + o;
        o += (bytes + 255) & ~(size_t)255;
        return p;
    };
    unsigned short* xb   = (unsigned short*)alloc((size_t)T_TOK * H_DIM * 2);
    unsigned short* xs   = (unsigned short*)alloc((size_t)T_TOK * H_DIM * 2);
    unsigned short* hmid = (unsigned short*)alloc((size_t)2 * T_TOK * I_DIM * 2);
    int* eidx    = (int*)alloc(T_TOK * 4);
    int* perm    = (int*)alloc(T_TOK * 4);
    int* off     = (int*)alloc(64 * 4);
    if (ws_size < o) return;  // insufficient workspace

    router_convert_kernel<<<T_TOK / 4, 256, 0, stream>>>(hs, rw, out_scores, eidx, xb, xs);
    group_kernel<<<1, 256, 0, stream>>>(eidx, perm, off);

    gemm1_kernel<<<dim3(I_DIM / BN, 9 * 8), 256, 0, stream>>>(
        xb, xs, gup, sg, su, perm, off, hmid);
    gemm2_kernel<0><<<dim3(H_DIM / BN, 8), 256, 0, stream>>>(hmid, dwn, sd, perm, off, out);
    gemm2_kernel<1><<<dim3(H_DIM / BN, E_NUM * 8), 256, 0, stream>>>(hmid, dwn, sd, perm, off, out);
}